// Round 2
// baseline (649.770 us; speedup 1.0000x reference)
//
#include <hip/hip_runtime.h>
#include <hip/hip_cooperative_groups.h>

namespace cg = cooperative_groups;

#define NUM_BINS 256
#define NPI (3*512*512)   // 786432 elements per image
#define TPB 256
#define MM_BLOCKS 16      // virtual blocks per image for minmax/hist/gather phases
#define NSUB 32           // LDS sub-histograms per block (2 lanes/wave per sub)
#define SUBSTRIDE 257     // 257 % 32 == 1: base bank of sub s is s -> spread
#define G_VEC 8           // packed uints (4 bins each) per thread per iter in gather

typedef float f32x4 __attribute__((ext_vector_type(4)));

// Must bit-match the f32 reference: (v-mn)*255 / (mx-mn+1e-8), clip, trunc.
// Keep the real division — a reciprocal precompute shifts boundary bins.
__device__ __forceinline__ int bin_of(float v, float mn, float denom) {
  float norm = (v - mn) * 255.0f / denom;
  norm = fminf(fmaxf(norm, 0.0f), 255.0f);
  return (int)norm;
}

__device__ __forceinline__ unsigned pack4(int b0, int b1, int b2, int b3) {
  return (unsigned)b0 | ((unsigned)b1 << 8) | ((unsigned)b2 << 16) | ((unsigned)b3 << 24);
}

// ---------------- fused cooperative kernel ----------------
// Phase bodies are identical to the verified split kernels; only the launch
// structure changed (grid.sync between phases instead of 4 dispatches).
__global__ void __launch_bounds__(TPB, 4)
fused_k(const float4* __restrict__ x, int B,
        float* __restrict__ mmn, float* __restrict__ mmx,
        int* __restrict__ histblk, float* __restrict__ cdfn,
        unsigned* __restrict__ bins32, float4* __restrict__ out,
        int use_bins) {
  cg::grid_group grid = cg::this_grid();
  __shared__ int sh[NSUB * SUBSTRIDE];   // 32.9 KB, reused by all phases
  __shared__ float smn[4], smx[4];
  __shared__ float s_mn, s_dn;
  const int nvb = B * MM_BLOCKS;
  const int chunk4 = NPI / 4 / MM_BLOCKS;  // 12288 float4 per virtual block

  // ---- phase 1: per-virtual-block min/max ----
  for (int vb = blockIdx.x; vb < nvb; vb += gridDim.x) {
    int img = vb / MM_BLOCKS, blk = vb % MM_BLOCKS;
    const float4* p = x + (size_t)img * (NPI/4) + (size_t)blk * chunk4;
    float mn = 3.4e38f, mx = -3.4e38f;
    for (int i = threadIdx.x; i < chunk4; i += TPB) {
      float4 v = p[i];
      mn = fminf(mn, fminf(fminf(v.x, v.y), fminf(v.z, v.w)));
      mx = fmaxf(mx, fmaxf(fmaxf(v.x, v.y), fmaxf(v.z, v.w)));
    }
    for (int off = 32; off > 0; off >>= 1) {
      mn = fminf(mn, __shfl_down(mn, off));
      mx = fmaxf(mx, __shfl_down(mx, off));
    }
    int wave = threadIdx.x >> 6, lane = threadIdx.x & 63;
    if (lane == 0) { smn[wave] = mn; smx[wave] = mx; }
    __syncthreads();
    if (threadIdx.x == 0) {
      mmn[vb] = fminf(fminf(smn[0], smn[1]), fminf(smn[2], smn[3]));
      mmx[vb] = fmaxf(fmaxf(smx[0], smx[1]), fmaxf(smx[2], smx[3]));
    }
    __syncthreads();
  }
  grid.sync();

  // ---- phase 2: histogram into LDS sub-hists + packed bin cache ----
  for (int vb = blockIdx.x; vb < nvb; vb += gridDim.x) {
    int img = vb / MM_BLOCKS, blk = vb % MM_BLOCKS;
    if (threadIdx.x < MM_BLOCKS) {
      float a = mmn[img * MM_BLOCKS + threadIdx.x];
      float b = mmx[img * MM_BLOCKS + threadIdx.x];
      for (int off = 8; off > 0; off >>= 1) {
        a = fminf(a, __shfl_down(a, off));
        b = fmaxf(b, __shfl_down(b, off));
      }
      if (threadIdx.x == 0) { s_mn = a; s_dn = b - a + 1e-8f; }
    }
    for (int i = threadIdx.x; i < NSUB * SUBSTRIDE; i += TPB) sh[i] = 0;
    __syncthreads();
    float mn = s_mn, denom = s_dn;
    size_t gbase = (size_t)img * (NPI/4) + (size_t)blk * chunk4;
    const float4* p = x + gbase;
    int* mysub = sh + (threadIdx.x & (NSUB - 1)) * SUBSTRIDE;
    for (int i = threadIdx.x; i < chunk4; i += TPB * 4) {
      float4 v0 = p[i];
      float4 v1 = p[i + TPB];
      float4 v2 = p[i + 2*TPB];
      float4 v3 = p[i + 3*TPB];
      int b00 = bin_of(v0.x, mn, denom), b01 = bin_of(v0.y, mn, denom);
      int b02 = bin_of(v0.z, mn, denom), b03 = bin_of(v0.w, mn, denom);
      int b10 = bin_of(v1.x, mn, denom), b11 = bin_of(v1.y, mn, denom);
      int b12 = bin_of(v1.z, mn, denom), b13 = bin_of(v1.w, mn, denom);
      int b20 = bin_of(v2.x, mn, denom), b21 = bin_of(v2.y, mn, denom);
      int b22 = bin_of(v2.z, mn, denom), b23 = bin_of(v2.w, mn, denom);
      int b30 = bin_of(v3.x, mn, denom), b31 = bin_of(v3.y, mn, denom);
      int b32 = bin_of(v3.z, mn, denom), b33 = bin_of(v3.w, mn, denom);
      atomicAdd(&mysub[b00], 1); atomicAdd(&mysub[b01], 1);
      atomicAdd(&mysub[b02], 1); atomicAdd(&mysub[b03], 1);
      atomicAdd(&mysub[b10], 1); atomicAdd(&mysub[b11], 1);
      atomicAdd(&mysub[b12], 1); atomicAdd(&mysub[b13], 1);
      atomicAdd(&mysub[b20], 1); atomicAdd(&mysub[b21], 1);
      atomicAdd(&mysub[b22], 1); atomicAdd(&mysub[b23], 1);
      atomicAdd(&mysub[b30], 1); atomicAdd(&mysub[b31], 1);
      atomicAdd(&mysub[b32], 1); atomicAdd(&mysub[b33], 1);
      if (use_bins) {
        bins32[gbase + i]         = pack4(b00, b01, b02, b03);
        bins32[gbase + i + TPB]   = pack4(b10, b11, b12, b13);
        bins32[gbase + i + 2*TPB] = pack4(b20, b21, b22, b23);
        bins32[gbase + i + 3*TPB] = pack4(b30, b31, b32, b33);
      }
    }
    __syncthreads();
    int bin = threadIdx.x;
    int s = 0;
    #pragma unroll
    for (int c2 = 0; c2 < NSUB; ++c2) s += sh[c2 * SUBSTRIDE + bin];
    histblk[vb * NUM_BINS + bin] = s;  // coalesced, no atomic
    __syncthreads();
  }
  grid.sync();

  // ---- phase 3: per-image scan (blocks 0..B-1) ----
  for (int img = blockIdx.x; img < B; img += gridDim.x) {
    int t = threadIdx.x;
    int v = 0;
    #pragma unroll
    for (int b = 0; b < MM_BLOCKS; ++b)
      v += histblk[(img * MM_BLOCKS + b) * NUM_BINS + t];
    sh[t] = v;
    __syncthreads();
    for (int off = 1; off < NUM_BINS; off <<= 1) {
      int add = (t >= off) ? sh[t - off] : 0;
      __syncthreads();
      sh[t] += add;
      __syncthreads();
    }
    int cdf = sh[t], c0 = sh[0], cN = sh[NUM_BINS - 1];
    // counts are exact integers < 2^24, so int math == the reference's f32 cumsum
    cdfn[img * NUM_BINS + t] = (float)(cdf - c0) / ((float)(cN - c0) + 1e-8f);
    __syncthreads();
  }
  grid.sync();

  // ---- phase 4: gather ----
  float* cf = (float*)sh;  // reuse LDS as the cdf table
  const int f4pi = NPI / 4;
  for (int vb = blockIdx.x; vb < nvb; vb += gridDim.x) {
    int img = vb / MM_BLOCKS, blk = vb % MM_BLOCKS;
    cf[threadIdx.x] = cdfn[img * NUM_BINS + threadIdx.x];  // TPB==NUM_BINS
    if (!use_bins && threadIdx.x < MM_BLOCKS) {
      float a = mmn[img * MM_BLOCKS + threadIdx.x];
      float b = mmx[img * MM_BLOCKS + threadIdx.x];
      for (int off = 8; off > 0; off >>= 1) {
        a = fminf(a, __shfl_down(a, off));
        b = fmaxf(b, __shfl_down(b, off));
      }
      if (threadIdx.x == 0) { s_mn = a; s_dn = b - a + 1e-8f; }
    }
    __syncthreads();
    size_t base = (size_t)img * f4pi + (size_t)blk * chunk4 + threadIdx.x;
    if (use_bins) {
      for (int it = 0; it < chunk4 / (TPB * G_VEC); ++it) {  // 6 iterations
        size_t b0 = base + (size_t)it * TPB * G_VEC;
        unsigned bv[G_VEC];
        #pragma unroll
        for (int j = 0; j < G_VEC; ++j) bv[j] = bins32[b0 + (size_t)j * TPB];
        #pragma unroll
        for (int j = 0; j < G_VEC; ++j) {
          unsigned b = bv[j];
          f32x4 o;
          o.x = cf[b & 255u];
          o.y = cf[(b >> 8) & 255u];
          o.z = cf[(b >> 16) & 255u];
          o.w = cf[b >> 24];
          // nontemporal: out is a pure stream; don't evict bins/x from LLC
          __builtin_nontemporal_store(o, (f32x4*)&out[b0 + (size_t)j * TPB]);
        }
      }
    } else {
      float mn = s_mn, denom = s_dn;
      for (int it = 0; it < chunk4 / (TPB * 4); ++it) {
        size_t b0 = base + (size_t)it * TPB * 4;
        #pragma unroll
        for (int j = 0; j < 4; ++j) {
          float4 v = x[b0 + (size_t)j * TPB];
          f32x4 o;
          o.x = cf[bin_of(v.x, mn, denom)];
          o.y = cf[bin_of(v.y, mn, denom)];
          o.z = cf[bin_of(v.z, mn, denom)];
          o.w = cf[bin_of(v.w, mn, denom)];
          __builtin_nontemporal_store(o, (f32x4*)&out[b0 + (size_t)j * TPB]);
        }
      }
    }
    __syncthreads();
  }
}

// ---------------- fallback split kernels (used only if cooperative launch fails) ----------------
__global__ void minmax_k(const float4* __restrict__ x,
                         float* __restrict__ mmn, float* __restrict__ mmx) {
  const int chunk4 = NPI / 4 / MM_BLOCKS;
  int img = blockIdx.x / MM_BLOCKS;
  int blk = blockIdx.x % MM_BLOCKS;
  const float4* p = x + (size_t)img * (NPI/4) + (size_t)blk * chunk4;
  float mn = 3.4e38f, mx = -3.4e38f;
  for (int i = threadIdx.x; i < chunk4; i += TPB) {
    float4 v = p[i];
    mn = fminf(mn, fminf(fminf(v.x, v.y), fminf(v.z, v.w)));
    mx = fmaxf(mx, fmaxf(fmaxf(v.x, v.y), fmaxf(v.z, v.w)));
  }
  for (int off = 32; off > 0; off >>= 1) {
    mn = fminf(mn, __shfl_down(mn, off));
    mx = fmaxf(mx, __shfl_down(mx, off));
  }
  __shared__ float smn[4], smx[4];
  int wave = threadIdx.x >> 6, lane = threadIdx.x & 63;
  if (lane == 0) { smn[wave] = mn; smx[wave] = mx; }
  __syncthreads();
  if (threadIdx.x == 0) {
    mmn[blockIdx.x] = fminf(fminf(smn[0], smn[1]), fminf(smn[2], smn[3]));
    mmx[blockIdx.x] = fmaxf(fmaxf(smx[0], smx[1]), fmaxf(smx[2], smx[3]));
  }
}

__global__ void hist_k(const float4* __restrict__ x,
                       const float* __restrict__ mmn, const float* __restrict__ mmx,
                       int* __restrict__ histblk, unsigned* __restrict__ bins32) {
  __shared__ int sh[NSUB * SUBSTRIDE];
  __shared__ float s_mn, s_dn;
  for (int i = threadIdx.x; i < NSUB * SUBSTRIDE; i += TPB) sh[i] = 0;
  const int chunk4 = NPI / 4 / MM_BLOCKS;
  int img = blockIdx.x / MM_BLOCKS;
  int blk = blockIdx.x % MM_BLOCKS;
  if (threadIdx.x < MM_BLOCKS) {
    float a = mmn[img * MM_BLOCKS + threadIdx.x];
    float b = mmx[img * MM_BLOCKS + threadIdx.x];
    for (int off = 8; off > 0; off >>= 1) {
      a = fminf(a, __shfl_down(a, off));
      b = fmaxf(b, __shfl_down(b, off));
    }
    if (threadIdx.x == 0) { s_mn = a; s_dn = b - a + 1e-8f; }
  }
  __syncthreads();
  float mn = s_mn, denom = s_dn;
  size_t gbase = (size_t)img * (NPI/4) + (size_t)blk * chunk4;
  const float4* p = x + gbase;
  int* mysub = sh + (threadIdx.x & (NSUB - 1)) * SUBSTRIDE;
  bool wb = (bins32 != nullptr);
  for (int i = threadIdx.x; i < chunk4; i += TPB * 4) {
    float4 v0 = p[i];
    float4 v1 = p[i + TPB];
    float4 v2 = p[i + 2*TPB];
    float4 v3 = p[i + 3*TPB];
    int b00 = bin_of(v0.x, mn, denom), b01 = bin_of(v0.y, mn, denom);
    int b02 = bin_of(v0.z, mn, denom), b03 = bin_of(v0.w, mn, denom);
    int b10 = bin_of(v1.x, mn, denom), b11 = bin_of(v1.y, mn, denom);
    int b12 = bin_of(v1.z, mn, denom), b13 = bin_of(v1.w, mn, denom);
    int b20 = bin_of(v2.x, mn, denom), b21 = bin_of(v2.y, mn, denom);
    int b22 = bin_of(v2.z, mn, denom), b23 = bin_of(v2.w, mn, denom);
    int b30 = bin_of(v3.x, mn, denom), b31 = bin_of(v3.y, mn, denom);
    int b32 = bin_of(v3.z, mn, denom), b33 = bin_of(v3.w, mn, denom);
    atomicAdd(&mysub[b00], 1); atomicAdd(&mysub[b01], 1);
    atomicAdd(&mysub[b02], 1); atomicAdd(&mysub[b03], 1);
    atomicAdd(&mysub[b10], 1); atomicAdd(&mysub[b11], 1);
    atomicAdd(&mysub[b12], 1); atomicAdd(&mysub[b13], 1);
    atomicAdd(&mysub[b20], 1); atomicAdd(&mysub[b21], 1);
    atomicAdd(&mysub[b22], 1); atomicAdd(&mysub[b23], 1);
    atomicAdd(&mysub[b30], 1); atomicAdd(&mysub[b31], 1);
    atomicAdd(&mysub[b32], 1); atomicAdd(&mysub[b33], 1);
    if (wb) {
      bins32[gbase + i]         = pack4(b00, b01, b02, b03);
      bins32[gbase + i + TPB]   = pack4(b10, b11, b12, b13);
      bins32[gbase + i + 2*TPB] = pack4(b20, b21, b22, b23);
      bins32[gbase + i + 3*TPB] = pack4(b30, b31, b32, b33);
    }
  }
  __syncthreads();
  int bin = threadIdx.x;
  int s = 0;
  #pragma unroll
  for (int c = 0; c < NSUB; ++c) s += sh[c * SUBSTRIDE + bin];
  histblk[blockIdx.x * NUM_BINS + bin] = s;
}

__global__ void scan_k(const int* __restrict__ histblk, float* __restrict__ cdfn) {
  __shared__ int s[NUM_BINS];
  int img = blockIdx.x, t = threadIdx.x;
  int v = 0;
  #pragma unroll
  for (int b = 0; b < MM_BLOCKS; ++b)
    v += histblk[(img * MM_BLOCKS + b) * NUM_BINS + t];
  s[t] = v;
  __syncthreads();
  for (int off = 1; off < NUM_BINS; off <<= 1) {
    int add = (t >= off) ? s[t - off] : 0;
    __syncthreads();
    s[t] += add;
    __syncthreads();
  }
  int cdf = s[t], c0 = s[0], cN = s[NUM_BINS - 1];
  cdfn[img * NUM_BINS + t] = (float)(cdf - c0) / ((float)(cN - c0) + 1e-8f);
}

__global__ void gather_bins_k(const unsigned* __restrict__ bins32,
                              const float* __restrict__ cdfn,
                              float4* __restrict__ out) {
  __shared__ float c[NUM_BINS];
  const int f4pi = NPI / 4;
  const int CHUNK = TPB * G_VEC;
  const int bpi = f4pi / CHUNK;
  int img = blockIdx.x / bpi;
  int blk = blockIdx.x % bpi;
  c[threadIdx.x] = cdfn[img * NUM_BINS + threadIdx.x];
  __syncthreads();
  size_t base = (size_t)img * f4pi + (size_t)blk * CHUNK + threadIdx.x;
  unsigned bv[G_VEC];
  #pragma unroll
  for (int j = 0; j < G_VEC; ++j) bv[j] = bins32[base + (size_t)j * TPB];
  #pragma unroll
  for (int j = 0; j < G_VEC; ++j) {
    unsigned b = bv[j];
    float4 o;
    o.x = c[b & 255u];
    o.y = c[(b >> 8) & 255u];
    o.z = c[(b >> 16) & 255u];
    o.w = c[b >> 24];
    out[base + (size_t)j * TPB] = o;
  }
}

__global__ void gather_x_k(const float4* __restrict__ x,
                           const float* __restrict__ mmn, const float* __restrict__ mmx,
                           const float* __restrict__ cdfn,
                           float4* __restrict__ out) {
  __shared__ float c[NUM_BINS];
  __shared__ float s_mn, s_dn;
  const int f4pi = NPI / 4;
  const int CHUNK = TPB * 4;
  const int bpi = f4pi / CHUNK;
  int img = blockIdx.x / bpi;
  int blk = blockIdx.x % bpi;
  c[threadIdx.x] = cdfn[img * NUM_BINS + threadIdx.x];
  if (threadIdx.x < MM_BLOCKS) {
    float a = mmn[img * MM_BLOCKS + threadIdx.x];
    float b = mmx[img * MM_BLOCKS + threadIdx.x];
    for (int off = 8; off > 0; off >>= 1) {
      a = fminf(a, __shfl_down(a, off));
      b = fmaxf(b, __shfl_down(b, off));
    }
    if (threadIdx.x == 0) { s_mn = a; s_dn = b - a + 1e-8f; }
  }
  __syncthreads();
  float mn = s_mn, denom = s_dn;
  size_t base = (size_t)img * f4pi + (size_t)blk * CHUNK + threadIdx.x;
  #pragma unroll
  for (int j = 0; j < 4; ++j) {
    float4 v = x[base + (size_t)j * TPB];
    float4 o;
    o.x = c[bin_of(v.x, mn, denom)];
    o.y = c[bin_of(v.y, mn, denom)];
    o.z = c[bin_of(v.z, mn, denom)];
    o.w = c[bin_of(v.w, mn, denom)];
    out[base + (size_t)j * TPB] = o;
  }
}

extern "C" void kernel_launch(void* const* d_in, const int* in_sizes, int n_in,
                              void* d_out, int out_size, void* d_ws, size_t ws_size,
                              hipStream_t stream) {
  const float* x = (const float*)d_in[0];
  float* out = (float*)d_out;
  int B = in_sizes[0] / NPI;  // 64 images

  // workspace layout:
  //   mmn:    B*16 f32        (per-block mins)
  //   mmx:    B*16 f32        (per-block maxs)
  //   histblk B*16*256 i32    (per-block histograms)
  //   cdfn:   B*256 f32
  //   bins:   B*NPI u8        (packed bin cache, optional)
  char* ws = (char*)d_ws;
  float* mmn = (float*)ws;
  float* mmx = mmn + (size_t)B * MM_BLOCKS;
  int* histblk = (int*)(mmx + (size_t)B * MM_BLOCKS);
  float* cdfn = (float*)(histblk + (size_t)B * MM_BLOCKS * NUM_BINS);
  unsigned* bins32 = (unsigned*)(cdfn + (size_t)B * NUM_BINS);
  size_t need = (size_t)((char*)bins32 - ws) + (size_t)B * NPI;
  int use_bins = (ws_size >= need) ? 1 : 0;

  // cooperative grid: clamp to co-resident capacity (queried once)
  static int max_blocks = -1;
  if (max_blocks < 0) {
    int per_cu = 0;
    if (hipOccupancyMaxActiveBlocksPerMultiprocessor(&per_cu, fused_k, TPB, 0)
            != hipSuccess || per_cu < 1)
      per_cu = 1;
    int ncu = 256;  // gfx950 default
    hipDeviceProp_t prop;
    if (hipGetDeviceProperties(&prop, 0) == hipSuccess && prop.multiProcessorCount > 0)
      ncu = prop.multiProcessorCount;
    max_blocks = per_cu * ncu;
  }
  int nvb = B * MM_BLOCKS;                       // 1024 virtual blocks
  int grid = (nvb < max_blocks) ? nvb : max_blocks;

  const float4* x4 = (const float4*)x;
  float4* out4 = (float4*)out;
  unsigned* binsp = use_bins ? bins32 : nullptr;
  void* kargs[] = { (void*)&x4, (void*)&B, (void*)&mmn, (void*)&mmx,
                    (void*)&histblk, (void*)&cdfn, (void*)&binsp, (void*)&out4,
                    (void*)&use_bins };
  hipError_t err = hipLaunchCooperativeKernel(fused_k, dim3(grid), dim3(TPB),
                                              kargs, 0, stream);
  if (err != hipSuccess) {
    // fallback: proven split-kernel path
    minmax_k<<<B * MM_BLOCKS, TPB, 0, stream>>>((const float4*)x, mmn, mmx);
    hist_k<<<B * MM_BLOCKS, TPB, 0, stream>>>((const float4*)x, mmn, mmx, histblk,
                                              use_bins ? bins32 : nullptr);
    scan_k<<<B, NUM_BINS, 0, stream>>>(histblk, cdfn);
    if (use_bins) {
      gather_bins_k<<<B * (NPI/4/(TPB*G_VEC)), TPB, 0, stream>>>(bins32, cdfn, (float4*)out);
    } else {
      gather_x_k<<<B * (NPI/4/(TPB*4)), TPB, 0, stream>>>((const float4*)x, mmn, mmx, cdfn,
                                                          (float4*)out);
    }
  }
}

// Round 4
// 375.959 us; speedup vs baseline: 1.7283x; 1.7283x over previous
//
#include <hip/hip_runtime.h>

#define NUM_BINS 256
#define NPI (3*512*512)   // 786432 elements per image
#define TPB 256
#define MMX_BLOCKS 32     // minmax blocks per image
#define MM_BLOCKS 16      // hist blocks per image
#define GB_PER_IMG 32     // gather blocks per image
#define NSUB 32           // LDS sub-histograms per block (2 lanes/wave per sub)
#define SUBSTRIDE 257     // 257 % 32 == 1: base bank of sub s is s -> spread
#define G_VEC 8           // packed uints (4 bins each) per thread per iter in gather

typedef float f32x4 __attribute__((ext_vector_type(4)));

// Must bit-match the f32 reference: (v-mn)*255 / (mx-mn+1e-8), clip, trunc.
// Keep the real division — a reciprocal precompute shifts boundary bins.
__device__ __forceinline__ int bin_of(float v, float mn, float denom) {
  float norm = (v - mn) * 255.0f / denom;
  norm = fminf(fmaxf(norm, 0.0f), 255.0f);
  return (int)norm;
}

__device__ __forceinline__ unsigned pack4(int b0, int b1, int b2, int b3) {
  return (unsigned)b0 | ((unsigned)b1 << 8) | ((unsigned)b2 << 16) | ((unsigned)b3 << 24);
}

// ---- pass 1: per-block min/max (plain f32 slots, no atomics) ----
// 2048 blocks (8/CU), 4 loads in flight per thread: latency-covered cold read.
__global__ void minmax_k(const float4* __restrict__ x,
                         float* __restrict__ mmn, float* __restrict__ mmx) {
  const int chunk4 = NPI / 4 / MMX_BLOCKS;  // 6144 float4 per block
  int img = blockIdx.x / MMX_BLOCKS;
  int blk = blockIdx.x % MMX_BLOCKS;
  const float4* p = x + (size_t)img * (NPI/4) + (size_t)blk * chunk4;
  float mn = 3.4e38f, mx = -3.4e38f;
  #pragma unroll 4
  for (int i = threadIdx.x; i < chunk4; i += TPB) {
    float4 v = p[i];
    mn = fminf(mn, fminf(fminf(v.x, v.y), fminf(v.z, v.w)));
    mx = fmaxf(mx, fmaxf(fmaxf(v.x, v.y), fmaxf(v.z, v.w)));
  }
  for (int off = 32; off > 0; off >>= 1) {
    mn = fminf(mn, __shfl_down(mn, off));
    mx = fmaxf(mx, __shfl_down(mx, off));
  }
  __shared__ float smn[4], smx[4];
  int wave = threadIdx.x >> 6, lane = threadIdx.x & 63;
  if (lane == 0) { smn[wave] = mn; smx[wave] = mx; }
  __syncthreads();
  if (threadIdx.x == 0) {
    mmn[blockIdx.x] = fminf(fminf(smn[0], smn[1]), fminf(smn[2], smn[3]));
    mmx[blockIdx.x] = fmaxf(fmaxf(smx[0], smx[1]), fmaxf(smx[2], smx[3]));
  }
}

__device__ __forceinline__ void load_minmax(const float* __restrict__ mmn,
                                            const float* __restrict__ mmx,
                                            int img, float* s_mn, float* s_dn) {
  if (threadIdx.x < MMX_BLOCKS) {  // 32 lanes, one wave
    float a = mmn[img * MMX_BLOCKS + threadIdx.x];
    float b = mmx[img * MMX_BLOCKS + threadIdx.x];
    for (int off = MMX_BLOCKS / 2; off > 0; off >>= 1) {
      a = fminf(a, __shfl_down(a, off));
      b = fmaxf(b, __shfl_down(b, off));
    }
    if (threadIdx.x == 0) { *s_mn = a; *s_dn = b - a + 1e-8f; }
  }
}

// ---- pass 2: histogram into LDS sub-hists + packed bin cache ----
// 8 float4 loads in flight per iteration (6 iterations); x is L3-warm.
__global__ void hist_k(const float4* __restrict__ x,
                       const float* __restrict__ mmn, const float* __restrict__ mmx,
                       int* __restrict__ histblk, unsigned* __restrict__ bins32) {
  __shared__ int sh[NSUB * SUBSTRIDE];
  __shared__ float s_mn, s_dn;
  load_minmax(mmn, mmx, blockIdx.x / MM_BLOCKS, &s_mn, &s_dn);
  for (int i = threadIdx.x; i < NSUB * SUBSTRIDE; i += TPB) sh[i] = 0;
  const int chunk4 = NPI / 4 / MM_BLOCKS;  // 12288
  int img = blockIdx.x / MM_BLOCKS;
  int blk = blockIdx.x % MM_BLOCKS;
  __syncthreads();
  float mn = s_mn, denom = s_dn;
  size_t gbase = (size_t)img * (NPI/4) + (size_t)blk * chunk4;
  const float4* p = x + gbase;
  int* mysub = sh + (threadIdx.x & (NSUB - 1)) * SUBSTRIDE;
  bool wb = (bins32 != nullptr);
  for (int i = threadIdx.x; i < chunk4; i += TPB * 8) {  // exactly 6 iterations
    float4 v[8];
    #pragma unroll
    for (int k = 0; k < 8; ++k) v[k] = p[i + k * TPB];
    int b[8][4];
    #pragma unroll
    for (int k = 0; k < 8; ++k) {
      b[k][0] = bin_of(v[k].x, mn, denom);
      b[k][1] = bin_of(v[k].y, mn, denom);
      b[k][2] = bin_of(v[k].z, mn, denom);
      b[k][3] = bin_of(v[k].w, mn, denom);
    }
    #pragma unroll
    for (int k = 0; k < 8; ++k) {
      atomicAdd(&mysub[b[k][0]], 1);
      atomicAdd(&mysub[b[k][1]], 1);
      atomicAdd(&mysub[b[k][2]], 1);
      atomicAdd(&mysub[b[k][3]], 1);
    }
    if (wb) {
      #pragma unroll
      for (int k = 0; k < 8; ++k)
        bins32[gbase + i + k * TPB] = pack4(b[k][0], b[k][1], b[k][2], b[k][3]);
    }
  }
  __syncthreads();
  int bin = threadIdx.x;
  int s = 0;
  #pragma unroll
  for (int c = 0; c < NSUB; ++c) s += sh[c * SUBSTRIDE + bin];
  histblk[blockIdx.x * NUM_BINS + bin] = s;  // coalesced, no atomic
}

// ---- pass 3: gather with folded scan ----
// Each block recomputes the per-image cdf from the 16 partial histograms
// (16 KB L2-hot read + 256-wide scan, ~µs across the grid) — saves a dispatch.
__global__ void gather_bins_k(const unsigned* __restrict__ bins32,
                              const int* __restrict__ histblk,
                              float4* __restrict__ out) {
  __shared__ int s[NUM_BINS];
  __shared__ float c[NUM_BINS];
  const int f4pi = NPI / 4;                    // 196608
  const int chunk4 = f4pi / GB_PER_IMG;        // 6144
  const int ITERS = chunk4 / (TPB * G_VEC);    // 3
  int img = blockIdx.x / GB_PER_IMG;
  int blk = blockIdx.x % GB_PER_IMG;
  int t = threadIdx.x;
  int v = 0;
  #pragma unroll
  for (int b = 0; b < MM_BLOCKS; ++b)
    v += histblk[(img * MM_BLOCKS + b) * NUM_BINS + t];
  s[t] = v;
  __syncthreads();
  for (int off = 1; off < NUM_BINS; off <<= 1) {
    int add = (t >= off) ? s[t - off] : 0;
    __syncthreads();
    s[t] += add;
    __syncthreads();
  }
  {
    int cdf = s[t], c0 = s[0], cN = s[NUM_BINS - 1];
    // counts are exact integers < 2^24, so int math == the reference's f32 cumsum
    c[t] = (float)(cdf - c0) / ((float)(cN - c0) + 1e-8f);
  }
  __syncthreads();
  size_t base = (size_t)img * f4pi + (size_t)blk * chunk4 + threadIdx.x;
  for (int it = 0; it < ITERS; ++it) {
    size_t b0 = base + (size_t)it * TPB * G_VEC;
    unsigned bv[G_VEC];
    #pragma unroll
    for (int j = 0; j < G_VEC; ++j) bv[j] = bins32[b0 + (size_t)j * TPB];
    #pragma unroll
    for (int j = 0; j < G_VEC; ++j) {
      unsigned b = bv[j];
      f32x4 o;
      o.x = c[b & 255u];
      o.y = c[(b >> 8) & 255u];
      o.z = c[(b >> 16) & 255u];
      o.w = c[b >> 24];
      // nontemporal: out is a pure stream; keep bins32/x resident in LLC
      __builtin_nontemporal_store(o, (f32x4*)&out[b0 + (size_t)j * TPB]);
    }
  }
}

// ---------------- fallback path (workspace too small for bin cache) ----------------
__global__ void scan_k(const int* __restrict__ histblk, float* __restrict__ cdfn) {
  __shared__ int s[NUM_BINS];
  int img = blockIdx.x, t = threadIdx.x;
  int v = 0;
  #pragma unroll
  for (int b = 0; b < MM_BLOCKS; ++b)
    v += histblk[(img * MM_BLOCKS + b) * NUM_BINS + t];
  s[t] = v;
  __syncthreads();
  for (int off = 1; off < NUM_BINS; off <<= 1) {
    int add = (t >= off) ? s[t - off] : 0;
    __syncthreads();
    s[t] += add;
    __syncthreads();
  }
  int cdf = s[t], c0 = s[0], cN = s[NUM_BINS - 1];
  cdfn[img * NUM_BINS + t] = (float)(cdf - c0) / ((float)(cN - c0) + 1e-8f);
}

__global__ void gather_x_k(const float4* __restrict__ x,
                           const float* __restrict__ mmn, const float* __restrict__ mmx,
                           const float* __restrict__ cdfn,
                           float4* __restrict__ out) {
  __shared__ float c[NUM_BINS];
  __shared__ float s_mn, s_dn;
  const int f4pi = NPI / 4;
  const int CHUNK = TPB * 4;
  const int bpi = f4pi / CHUNK;  // 192
  int img = blockIdx.x / bpi;
  int blk = blockIdx.x % bpi;
  c[threadIdx.x] = cdfn[img * NUM_BINS + threadIdx.x];
  load_minmax(mmn, mmx, img, &s_mn, &s_dn);
  __syncthreads();
  float mn = s_mn, denom = s_dn;
  size_t base = (size_t)img * f4pi + (size_t)blk * CHUNK + threadIdx.x;
  #pragma unroll
  for (int j = 0; j < 4; ++j) {
    float4 v = x[base + (size_t)j * TPB];
    f32x4 o;
    o.x = c[bin_of(v.x, mn, denom)];
    o.y = c[bin_of(v.y, mn, denom)];
    o.z = c[bin_of(v.z, mn, denom)];
    o.w = c[bin_of(v.w, mn, denom)];
    __builtin_nontemporal_store(o, (f32x4*)&out[base + (size_t)j * TPB]);
  }
}

extern "C" void kernel_launch(void* const* d_in, const int* in_sizes, int n_in,
                              void* d_out, int out_size, void* d_ws, size_t ws_size,
                              hipStream_t stream) {
  const float* x = (const float*)d_in[0];
  float* out = (float*)d_out;
  int B = in_sizes[0] / NPI;  // 64 images

  // workspace layout:
  //   mmn:    B*32 f32        (per-block mins)
  //   mmx:    B*32 f32        (per-block maxs)
  //   histblk B*16*256 i32    (per-block histograms)
  //   cdfn:   B*256 f32       (fallback only)
  //   bins:   B*NPI u8        (packed bin cache, optional)
  char* ws = (char*)d_ws;
  float* mmn = (float*)ws;
  float* mmx = mmn + (size_t)B * MMX_BLOCKS;
  int* histblk = (int*)(mmx + (size_t)B * MMX_BLOCKS);
  float* cdfn = (float*)(histblk + (size_t)B * MM_BLOCKS * NUM_BINS);
  unsigned* bins32 = (unsigned*)(cdfn + (size_t)B * NUM_BINS);
  size_t need = (size_t)((char*)bins32 - ws) + (size_t)B * NPI;
  bool use_bins = (ws_size >= need);

  minmax_k<<<B * MMX_BLOCKS, TPB, 0, stream>>>((const float4*)x, mmn, mmx);
  hist_k<<<B * MM_BLOCKS, TPB, 0, stream>>>((const float4*)x, mmn, mmx, histblk,
                                            use_bins ? bins32 : nullptr);
  if (use_bins) {
    gather_bins_k<<<B * GB_PER_IMG, TPB, 0, stream>>>(bins32, histblk, (float4*)out);
  } else {
    scan_k<<<B, NUM_BINS, 0, stream>>>(histblk, cdfn);
    gather_x_k<<<B * (NPI/4/(TPB*4)), TPB, 0, stream>>>((const float4*)x, mmn, mmx, cdfn,
                                                        (float4*)out);
  }
}